// Round 1
// baseline (65.105 us; speedup 1.0000x reference)
//
#include <hip/hip_runtime.h>

#define TI 256   // i's per block (== blockDim.x)
#define TJ 512   // j-chunk per block (grid.y dimension)

__global__ void prl_pairs(const float* __restrict__ pred,
                          const int* __restrict__ targ,
                          int n, double* __restrict__ acc) {
    __shared__ float sp[TI];
    __shared__ int   st[TI];

    const int tid = threadIdx.x;
    const int i   = blockIdx.x * TI + tid;
    const bool vi = (i < n);
    const float pi = vi ? pred[i] : 0.0f;
    const int   ti = vi ? targ[i] : 0x7fffffff;  // INT_MAX: ti < tj never true

    float        s = 0.0f;
    unsigned int c = 0;

    const int j0 = blockIdx.y * TJ;
    const int j1 = (j0 + TJ < n) ? (j0 + TJ) : n;

    for (int jb = j0; jb < j1; jb += TI) {
        const int j = jb + tid;
        if (j < j1) {
            sp[tid] = pred[j];
            st[tid] = targ[j];
        } else {
            sp[tid] = 0.0f;
            st[tid] = (int)0x80000000;  // INT_MIN: ti < tj never true
        }
        __syncthreads();

        const int lim = (j1 - jb < TI) ? (j1 - jb) : TI;
        #pragma unroll 8
        for (int k = 0; k < lim; ++k) {
            const float pj = sp[k];
            const int   tj = st[k];
            if (ti < tj) {
                s += fmaxf(1.0f - (pj - pi), 0.0f);
                ++c;
            }
        }
        __syncthreads();
    }

    // wave-64 reduction
    for (int off = 32; off; off >>= 1) {
        s += __shfl_down(s, off);
        c += __shfl_down(c, off);
    }

    __shared__ float        wsum[TI / 64];
    __shared__ unsigned int wcnt[TI / 64];
    const int wave = tid >> 6;
    if ((tid & 63) == 0) { wsum[wave] = s; wcnt[wave] = c; }
    __syncthreads();

    if (tid == 0) {
        float              bs = 0.0f;
        unsigned long long bc = 0;
        #pragma unroll
        for (int w = 0; w < TI / 64; ++w) { bs += wsum[w]; bc += wcnt[w]; }
        atomicAdd(acc, (double)bs);
        atomicAdd((unsigned long long*)(acc + 1), bc);
    }
}

__global__ void prl_final(const double* __restrict__ acc, float* __restrict__ out) {
    const double             t = acc[0];
    const unsigned long long c = *(const unsigned long long*)(acc + 1);
    out[0] = (c > 0) ? (float)(t / (double)c) : 0.0f;
}

extern "C" void kernel_launch(void* const* d_in, const int* in_sizes, int n_in,
                              void* d_out, int out_size, void* d_ws, size_t ws_size,
                              hipStream_t stream) {
    const float* pred = (const float*)d_in[0];
    const int*   targ = (const int*)d_in[1];
    float*       out  = (float*)d_out;
    const int    n    = in_sizes[0];

    double* acc = (double*)d_ws;
    hipMemsetAsync(acc, 0, 2 * sizeof(double), stream);

    dim3 grid((n + TI - 1) / TI, (n + TJ - 1) / TJ);
    prl_pairs<<<grid, TI, 0, stream>>>(pred, targ, n, acc);
    prl_final<<<1, 1, 0, stream>>>(acc, out);
}

// Round 2
// 20.267 us; speedup vs baseline: 3.2123x; 3.2123x over previous
//
#include <hip/hip_runtime.h>

#define BLOCK 256
#define IPT   8                 // i's per thread (8 independent acc chains)
#define TJ    64                // j-chunk per block
#define ITILE (BLOCK * IPT)     // 2048 i's per block

__global__ __launch_bounds__(BLOCK) void prl_pairs(
    const float* __restrict__ pred,
    const int*   __restrict__ targ,
    int n, float* __restrict__ partials)
{
    __shared__ float2 sj[TJ];          // x = 1 - pred[j], y = bitcast(targ[j])
    __shared__ float  wsum[BLOCK / 64];

    const int tid = threadIdx.x;
    const int i0  = blockIdx.x * ITILE;
    const int j0  = blockIdx.y * TJ;

    float pi[IPT]; int ti[IPT]; float s[IPT];
    #pragma unroll
    for (int m = 0; m < IPT; ++m) {
        const int  i = i0 + m * BLOCK + tid;
        const bool v = (i < n);
        pi[m] = v ? pred[i] : 0.0f;
        ti[m] = v ? targ[i] : 0x7fffffff;      // INT_MAX: never < tj
        s[m]  = 0.0f;
    }

    if (tid < TJ) {
        const int  j = j0 + tid;
        const bool v = (j < n);
        const float q  = v ? (1.0f - pred[j]) : 0.0f;
        const int   tj = v ? targ[j] : (int)0x80000000;  // INT_MIN: ti < tj never
        sj[tid] = make_float2(q, __int_as_float(tj));
    }
    __syncthreads();

    #pragma unroll 2
    for (int k = 0; k < TJ; ++k) {
        const float2 v  = sj[k];          // one ds_read_b64, wave-broadcast
        const float  q  = v.x;            // 1 - pj
        const int    tj = __float_as_int(v.y);
        #pragma unroll
        for (int m = 0; m < IPT; ++m) {
            const float h = fmaxf(pi[m] + q, 0.0f);   // max(1 - (pj - pi), 0)
            if (ti[m] < tj) s[m] += h;                // predicated cndmask+add
        }
    }

    float st = 0.0f;
    #pragma unroll
    for (int m = 0; m < IPT; ++m) st += s[m];
    #pragma unroll
    for (int off = 32; off; off >>= 1) st += __shfl_down(st, off);

    const int wave = tid >> 6;
    if ((tid & 63) == 0) wsum[wave] = st;
    __syncthreads();
    if (tid == 0) {
        float b = 0.0f;
        #pragma unroll
        for (int w = 0; w < BLOCK / 64; ++w) b += wsum[w];
        partials[blockIdx.y * gridDim.x + blockIdx.x] = b;  // no atomics
    }
}

__global__ __launch_bounds__(256) void prl_final(
    const float* __restrict__ partials, int nparts,
    const int*   __restrict__ targ, int n, float* __restrict__ out)
{
    __shared__ int    hist[32];
    __shared__ double wsum[4];
    const int tid = threadIdx.x;

    if (tid < 32) hist[tid] = 0;
    __syncthreads();
    for (int i = tid; i < n; i += 256) atomicAdd(&hist[targ[i] & 31], 1);

    double s = 0.0;
    for (int i = tid; i < nparts; i += 256) s += (double)partials[i];
    #pragma unroll
    for (int off = 32; off; off >>= 1) s += __shfl_down(s, off);
    if ((tid & 63) == 0) wsum[tid >> 6] = s;
    __syncthreads();

    if (tid == 0) {
        const double tot = wsum[0] + wsum[1] + wsum[2] + wsum[3];
        long long sq = 0;
        #pragma unroll
        for (int v = 0; v < 32; ++v) { const long long h = hist[v]; sq += h * h; }
        const long long cnt = ((long long)n * (long long)n - sq) / 2;  // #(t_i < t_j)
        out[0] = (cnt > 0) ? (float)(tot / (double)cnt) : 0.0f;
    }
}

extern "C" void kernel_launch(void* const* d_in, const int* in_sizes, int n_in,
                              void* d_out, int out_size, void* d_ws, size_t ws_size,
                              hipStream_t stream) {
    const float* pred = (const float*)d_in[0];
    const int*   targ = (const int*)d_in[1];
    float*       out  = (float*)d_out;
    const int    n    = in_sizes[0];

    float* partials = (float*)d_ws;
    const int gx = (n + ITILE - 1) / ITILE;   // 4  for n=8192
    const int gy = (n + TJ - 1) / TJ;         // 128
    prl_pairs<<<dim3(gx, gy), BLOCK, 0, stream>>>(pred, targ, n, partials);
    prl_final<<<1, 256, 0, stream>>>(partials, gx * gy, targ, n, out);
}